// Round 4
// baseline (147.978 us; speedup 1.0000x reference)
//
#include <hip/hip_runtime.h>
#include <math.h>

#define TPB 512

// ---------------------------------------------------------------------------
// Prep: (a) fused head table wq[hw*128+c] = {bw0,bw1,bw2, patc} where
// patc = sum_{k: psi[k]==c} pat_w[hw*32+k]; (b) transposed conv weights
// cwT[c*32 + k]: k<27 -> conv_w[k][c], 27 -> conv_b[c], 28 -> match_w[c].
// ---------------------------------------------------------------------------
__global__ __launch_bounds__(256)
void prep_weights(const float* __restrict__ base_w,  // [131072,3]
                  const float* __restrict__ pat_w,   // [32768]
                  const int*   __restrict__ psi,     // [32]
                  const float* __restrict__ conv_w,  // [27,128]
                  const float* __restrict__ conv_b,  // [128]
                  const float* __restrict__ match_w, // [128]
                  float4* __restrict__ wq,           // [131072]
                  float*  __restrict__ cwT)          // [128*32]
{
    int idx = blockIdx.x * 256 + threadIdx.x;        // 0..131071
    int hw = idx >> 7, c = idx & 127;
    const float* bp = base_w + (size_t)idx * 3;
    float b0 = bp[0], b1 = bp[1], b2 = bp[2];
    float pc = 0.f;
    const float* pr = pat_w + hw * 32;
    #pragma unroll
    for (int k = 0; k < 32; ++k)
        pc += (psi[k] == c) ? pr[k] : 0.f;
    wq[idx] = make_float4(b0, b1, b2, pc);

    if (idx < 4096) {
        int cc = idx >> 5, k = idx & 31;
        float v = 0.f;
        if (k < 27)       v = conv_w[k * 128 + cc];
        else if (k == 27) v = conv_b[cc];
        else if (k == 28) v = match_w[cc];
        cwT[idx] = v;
    }
}

// ---------------------------------------------------------------------------
// Main: lane = sample (64/wave), wave = 16-channel subset, block = 8-px slice.
// grid = 512 blocks: bx = slice*4 + sg; slice = (oh, ow-quarter); sg picks
// samples 64*sg..64*sg+63. All weights wave-uniform -> s_load (SGPRs);
// input window in LDS [row][float][sample] (lane stride 4 B, conflict-free).
// Inner loop per (px,ch): 27 v_fmac(s,v) + relu + 5 head v_fmac. Partials
// out to ws; finalize kernel routes.
// ---------------------------------------------------------------------------
__global__ __launch_bounds__(TPB, 8)
void pattern_branch_kernel(const float* __restrict__ in,      // [256,64,64,3]
                           const float* __restrict__ cwT,     // [128*32]
                           const float* __restrict__ wq,      // [131072*4]
                           float* __restrict__ part)          // [5][256][128]
{
    __shared__ float xs[3 * 52 * 64];     // 39936 B: [r][f 0..51][s]
    __shared__ float red[8][5][64];       // 10240 B

    const int bx    = blockIdx.x;
    const int sg    = bx & 3;
    const int slice = bx >> 2;            // 0..127
    const int oh    = slice >> 2;         // 0..31
    const int owq   = slice & 3;          // ow in [8*owq, 8*owq+8)
    const int tid   = threadIdx.x;

    // ---- pre-zero x (covers SAME pad: ih==64 row, iw==64 col, owq=3 tail)
    for (int i = tid; i < 3 * 52 * 64; i += TPB) xs[i] = 0.f;
    __syncthreads();

    // ---- stage: rows ih = 2*oh + r (r=0..2), floats 48*owq .. +52 per row
    {
        const int s = tid & 63;
        const float4* src = (const float4*)in + (size_t)(64 * sg + s) * 3072;
        const int nq = (owq < 3) ? 13 : 12;    // owq=3: floats 144..191 only
        for (int idx = tid >> 6; idx < 39; idx += 8) {
            int r = idx / 13, q = idx - r * 13;
            int ih = 2 * oh + r;
            if (ih < 64 && q < nq) {
                float4 v = src[ih * 48 + 12 * owq + q];
                int f = 4 * q;
                xs[(r * 52 + f)     * 64 + s] = v.x;
                xs[(r * 52 + f + 1) * 64 + s] = v.y;
                xs[(r * 52 + f + 2) * 64 + s] = v.z;
                xs[(r * 52 + f + 3) * 64 + s] = v.w;
            }
        }
    }
    __syncthreads();

    const int s  = tid & 63;
    const int wv = __builtin_amdgcn_readfirstlane(tid >> 6);  // wave id, uniform
    float sm = 0.f, s0 = 0.f, s1 = 0.f, s2 = 0.f, sp = 0.f;
    const int hwbase = oh * 32 + 8 * owq;

    for (int px = 0; px < 8; ++px) {
        // x window: f = 6*px + t9 per kh-row; loaded once, reused for 16 ch
        float x[27];
        #pragma unroll
        for (int kh = 0; kh < 3; ++kh)
            #pragma unroll
            for (int t = 0; t < 9; ++t)
                x[kh * 9 + t] = xs[(kh * 52 + 6 * px + t) * 64 + s];

        const float* wqp = wq + (size_t)(hwbase + px) * 512;  // 128 * float4
        #pragma unroll 2
        for (int j = 0; j < 16; ++j) {
            int c = wv * 16 + j;                 // wave-uniform channel
            const float* cw = cwT + c * 32;      // -> s_load_dwordx16 x2
            float acc = cw[27];                  // bias
            #pragma unroll
            for (int k = 0; k < 27; ++k) acc = fmaf(x[k], cw[k], acc);
            float f = fmaxf(acc, 0.f);
            const float* q4 = wqp + c * 4;       // -> s_load_dwordx4
            sm = fmaf(cw[28], f, sm);
            s0 = fmaf(f, q4[0], s0);
            s1 = fmaf(f, q4[1], s1);
            s2 = fmaf(f, q4[2], s2);
            sp = fmaf(f, q4[3], sp);
        }
    }

    // ---- cross-wave reduction (lanes are samples; no intra-wave reduce)
    red[wv][0][s] = sm; red[wv][1][s] = s0; red[wv][2][s] = s1;
    red[wv][3][s] = s2; red[wv][4][s] = sp;
    __syncthreads();
    if (tid < 320) {
        int v = tid >> 6, ss = tid & 63;
        float a = 0.f;
        #pragma unroll
        for (int w2 = 0; w2 < 8; ++w2) a += red[w2][v][ss];
        // part[v][sample][slice]
        part[((size_t)v * 256 + 64 * sg + ss) * 128 + slice] = a;
    }
}

// ---------------------------------------------------------------------------
// Finalize: thread b sums 128 slice-partials per head and routes.
// ---------------------------------------------------------------------------
__global__ __launch_bounds__(256)
void finalize_kernel(const float* __restrict__ part,    // [5][256][128]
                     const float* __restrict__ match_b,
                     const float* __restrict__ pat_b,
                     const float* __restrict__ base_b,
                     float* __restrict__ out)           // [256,3]
{
    int b = threadIdx.x;
    float t[5];
    #pragma unroll
    for (int v = 0; v < 5; ++v) {
        const float4* p4 = (const float4*)(part + ((size_t)v * 256 + b) * 128);
        float a = 0.f;
        #pragma unroll
        for (int i = 0; i < 32; ++i) {
            float4 u = p4[i];
            a += (u.x + u.y) + (u.z + u.w);
        }
        t[v] = a;
    }
    float score = t[0] * (1.f / 1024.f) + match_b[0];
    float p = 1.f / (1.f + expf(-(t[4] + pat_b[0])));
    float l0 = t[1] + base_b[0], l1 = t[2] + base_b[1], l2 = t[3] + base_b[2];
    float m = fmaxf(l0, fmaxf(l1, l2));
    float e0 = expf(l0 - m), e1 = expf(l1 - m), e2 = expf(l2 - m);
    float inv = 1.f / (e0 + e1 + e2);
    bool use_pat = (score > 0.f) && (p >= 0.5f);
    float o0, o1, o2;
    if (use_pat) { o0 = p; o1 = 0.5f * (1.f - p); o2 = o1; }
    else         { o0 = e0 * inv; o1 = e1 * inv; o2 = e2 * inv; }
    out[b * 3 + 0] = o0;
    out[b * 3 + 1] = o1;
    out[b * 3 + 2] = o2;
}

extern "C" void kernel_launch(void* const* d_in, const int* in_sizes, int n_in,
                              void* d_out, int out_size, void* d_ws, size_t ws_size,
                              hipStream_t stream) {
    const float* in      = (const float*)d_in[0];
    const float* conv_w  = (const float*)d_in[1];
    const float* conv_b  = (const float*)d_in[2];
    const float* match_w = (const float*)d_in[3];
    const float* match_b = (const float*)d_in[4];
    const float* pat_w   = (const float*)d_in[5];
    const float* pat_b   = (const float*)d_in[6];
    const float* base_w  = (const float*)d_in[7];
    const float* base_b  = (const float*)d_in[8];
    const int*   psi     = (const int*)d_in[9];
    float* out = (float*)d_out;

    char* ws = (char*)d_ws;
    float4* wq   = (float4*)ws;                              // 2 MB
    float*  cwT  = (float*)(ws + (size_t)131072 * 16);       // 16 KB
    float*  part = (float*)(ws + (size_t)131072 * 16 + 16384); // 640 KB

    prep_weights<<<512, 256, 0, stream>>>(base_w, pat_w, psi,
                                          conv_w, conv_b, match_w, wq, cwT);

    pattern_branch_kernel<<<512, TPB, 0, stream>>>(in, cwT, (const float*)wq, part);

    finalize_kernel<<<1, 256, 0, stream>>>(part, match_b, pat_b, base_b, out);
}

// Round 5
// 123.531 us; speedup vs baseline: 1.1979x; 1.1979x over previous
//
#include <hip/hip_runtime.h>
#include <math.h>

#define TPB 512

// ---------------------------------------------------------------------------
// Prep: fused head table in iteration-friendly layout.
// wq2[((hw>>2)*128 + c)*4 + (hw&3)] = {bw0, bw1, bw2, patc}
// patc = sum_{k: psi[k]==c} pat_w[hw*32+k]  (pat head is linear in feats).
// A main-kernel iteration needs hw = 4t..4t+3 for one c -> 4 consecutive
// float4 at one base (imm offsets 0/16/32/48 B), base advances 8 KB/iter.
// ---------------------------------------------------------------------------
__global__ __launch_bounds__(256)
void prep_weights(const float* __restrict__ base_w,  // [131072,3]
                  const float* __restrict__ pat_w,   // [32768]
                  const int*   __restrict__ psi,     // [32]
                  float4* __restrict__ wq2)          // [131072]
{
    int idx = blockIdx.x * 256 + threadIdx.x;        // 0..131071
    int hw = idx >> 7, c = idx & 127;
    const float* bp = base_w + (size_t)idx * 3;
    float b0 = bp[0], b1 = bp[1], b2 = bp[2];
    float pc = 0.f;
    const float* pr = pat_w + hw * 32;
    #pragma unroll
    for (int k = 0; k < 32; ++k)
        pc += (psi[k] == c) ? pr[k] : 0.f;
    wq2[(size_t)((hw >> 2) * 128 + c) * 4 + (hw & 3)] = make_float4(b0, b1, b2, pc);
}

// ---------------------------------------------------------------------------
// Main: 4 blocks/sample (quarter = 8 output rows), 512 threads.
// Lane = channel (c = tid&127; full-wave-uniform spatial slot -> x reads are
// LDS broadcasts). Conv weights pinned in VGPRs via asm barrier (no remat).
// sg = tid>>7 picks oh_loc pair; 16 iters x 4 ow. Head weights from wq2,
// one linear base pointer. Partials to ws; finalize kernel routes.
// ---------------------------------------------------------------------------
__global__ __launch_bounds__(TPB, 6)
void pattern_branch_kernel(const float* __restrict__ in,      // [256,64,64,3]
                           const float* __restrict__ conv_w,  // [27,128]
                           const float* __restrict__ conv_b,  // [128]
                           const float* __restrict__ match_w, // [128]
                           const float4* __restrict__ wq2,    // [131072]
                           float* __restrict__ part)          // [4][5][256]
{
    constexpr int ROWF4 = 50;              // float4 per padded row
    __shared__ float4 xlds4[17 * ROWF4];   // 13.6 KB
    __shared__ float  red[8][5];

    const int bx  = blockIdx.x;
    const int qh  = bx >> 8;               // quarter 0..3
    const int b   = bx & 255;
    const int tid = threadIdx.x;

    // ---- stage 17 input rows (ih = 16*qh..16*qh+16), zero row 64 / col pad
    for (int s = tid; s < 17 * ROWF4; s += TPB) xlds4[s] = make_float4(0.f, 0.f, 0.f, 0.f);
    __syncthreads();
    const float4* inp4 = (const float4*)(in + (size_t)b * 12288);
    for (int s = tid; s < 17 * 48; s += TPB) {
        int r  = s / 48;
        int qq = s - r * 48;
        int ih = 16 * qh + r;
        if (ih < 64) xlds4[r * ROWF4 + qq] = inp4[ih * 48 + qq];
    }
    __syncthreads();

    // ---- conv weights: one channel per thread, PINNED in VGPRs
    const int c  = tid & 127;
    const int sg = tid >> 7;               // 0..3
    float w[27];
    #pragma unroll
    for (int k = 0; k < 27; ++k) w[k] = conv_w[k * 128 + c];
    float bias = conv_b[c];
    float mw   = match_w[c];
    #pragma unroll
    for (int k = 0; k < 27; ++k) asm volatile("" : "+v"(w[k]));
    asm volatile("" : "+v"(bias), "+v"(mw));

    float sm = 0.f, s0 = 0.f, s1 = 0.f, s2 = 0.f, sp = 0.f;

    // hwslot = (8*qh + 2*sg)*8 + it  (advances by 1 -> wq base += 8192 B/iter)
    const float4* wqp = wq2 + (size_t)((8 * qh + 2 * sg) * 8) * 512 / 4 * 4; // base
    wqp = wq2 + (size_t)((8 * qh + 2 * sg) * 8 * 128 + c) * 4;

    for (int it = 0; it < 16; ++it) {
        const int oh_loc = 2 * sg + (it >> 3);
        const int q      = it & 7;

        float acc0 = bias, acc1 = bias, acc2 = bias, acc3 = bias;
        #pragma unroll
        for (int kh = 0; kh < 3; ++kh) {
            const float4* rp = &xlds4[(4 * sg + 2 * (it >> 3) + kh) * ROWF4 + 6 * q];
            const float* wk = &w[kh * 9];
            {   // first half: v=0 (floats 0..8), v=1 (floats 6..14)
                float4 t0 = rp[0], t1 = rp[1], t2 = rp[2], t3 = rp[3];
                acc0 = fmaf(t0.x, wk[0], acc0); acc0 = fmaf(t0.y, wk[1], acc0);
                acc0 = fmaf(t0.z, wk[2], acc0); acc0 = fmaf(t0.w, wk[3], acc0);
                acc0 = fmaf(t1.x, wk[4], acc0); acc0 = fmaf(t1.y, wk[5], acc0);
                acc0 = fmaf(t1.z, wk[6], acc0); acc0 = fmaf(t1.w, wk[7], acc0);
                acc0 = fmaf(t2.x, wk[8], acc0);
                acc1 = fmaf(t1.z, wk[0], acc1); acc1 = fmaf(t1.w, wk[1], acc1);
                acc1 = fmaf(t2.x, wk[2], acc1); acc1 = fmaf(t2.y, wk[3], acc1);
                acc1 = fmaf(t2.z, wk[4], acc1); acc1 = fmaf(t2.w, wk[5], acc1);
                acc1 = fmaf(t3.x, wk[6], acc1); acc1 = fmaf(t3.y, wk[7], acc1);
                acc1 = fmaf(t3.z, wk[8], acc1);
            }
            {   // second half: v=2 (floats 12..20), v=3 (floats 18..26)
                float4 t3 = rp[3], t4 = rp[4], t5 = rp[5], t6 = rp[6];
                acc2 = fmaf(t3.x, wk[0], acc2); acc2 = fmaf(t3.y, wk[1], acc2);
                acc2 = fmaf(t3.z, wk[2], acc2); acc2 = fmaf(t3.w, wk[3], acc2);
                acc2 = fmaf(t4.x, wk[4], acc2); acc2 = fmaf(t4.y, wk[5], acc2);
                acc2 = fmaf(t4.z, wk[6], acc2); acc2 = fmaf(t4.w, wk[7], acc2);
                acc2 = fmaf(t5.x, wk[8], acc2);
                acc3 = fmaf(t4.z, wk[0], acc3); acc3 = fmaf(t4.w, wk[1], acc3);
                acc3 = fmaf(t5.x, wk[2], acc3); acc3 = fmaf(t5.y, wk[3], acc3);
                acc3 = fmaf(t5.z, wk[4], acc3); acc3 = fmaf(t5.w, wk[5], acc3);
                acc3 = fmaf(t6.x, wk[6], acc3); acc3 = fmaf(t6.y, wk[7], acc3);
                acc3 = fmaf(t6.z, wk[8], acc3);
            }
        }
        // heads: 4 consecutive float4 at one base (imm offsets 0/16/32/48)
        float4 wv0 = wqp[0], wv1 = wqp[1], wv2 = wqp[2], wv3 = wqp[3];
        wqp += 512;                        // next iteration's slot (+8192 B)

        float f0 = fmaxf(acc0, 0.f), f1 = fmaxf(acc1, 0.f);
        float f2 = fmaxf(acc2, 0.f), f3 = fmaxf(acc3, 0.f);
        sm = fmaf(mw, (f0 + f1) + (f2 + f3), sm);
        s0 = fmaf(f0, wv0.x, s0); s1 = fmaf(f0, wv0.y, s1);
        s2 = fmaf(f0, wv0.z, s2); sp = fmaf(f0, wv0.w, sp);
        s0 = fmaf(f1, wv1.x, s0); s1 = fmaf(f1, wv1.y, s1);
        s2 = fmaf(f1, wv1.z, s2); sp = fmaf(f1, wv1.w, sp);
        s0 = fmaf(f2, wv2.x, s0); s1 = fmaf(f2, wv2.y, s1);
        s2 = fmaf(f2, wv2.z, s2); sp = fmaf(f2, wv2.w, sp);
        s0 = fmaf(f3, wv3.x, s0); s1 = fmaf(f3, wv3.y, s1);
        s2 = fmaf(f3, wv3.z, s2); sp = fmaf(f3, wv3.w, sp);
        (void)oh_loc; (void)q;
    }

    // ---- reduction: wave shuffle (lanes=channels), then LDS across 8 waves
    float vals[5] = { sm, s0, s1, s2, sp };
    #pragma unroll
    for (int off = 32; off > 0; off >>= 1)
        #pragma unroll
        for (int v = 0; v < 5; ++v)
            vals[v] += __shfl_down(vals[v], off, 64);
    int wv = tid >> 6, lane = tid & 63;
    if (lane == 0) {
        #pragma unroll
        for (int v = 0; v < 5; ++v) red[wv][v] = vals[v];
    }
    __syncthreads();
    if (tid == 0) {
        #pragma unroll
        for (int v = 0; v < 5; ++v) {
            float t = 0.f;
            for (int wj = 0; wj < 8; ++wj) t += red[wj][v];
            part[(qh * 5 + v) * 256 + b] = t;
        }
    }
}

// ---------------------------------------------------------------------------
// Finalize: thread b sums the 4 quarter-partials and routes.
// ---------------------------------------------------------------------------
__global__ __launch_bounds__(256)
void finalize_kernel(const float* __restrict__ part,    // [4][5][256]
                     const float* __restrict__ match_b,
                     const float* __restrict__ pat_b,
                     const float* __restrict__ base_b,
                     float* __restrict__ out)           // [256,3]
{
    int b = threadIdx.x;
    float t[5] = { 0.f, 0.f, 0.f, 0.f, 0.f };
    #pragma unroll
    for (int j = 0; j < 4; ++j)
        #pragma unroll
        for (int v = 0; v < 5; ++v)
            t[v] += part[(j * 5 + v) * 256 + b];
    float score = t[0] * (1.f / 1024.f) + match_b[0];
    float p = 1.f / (1.f + expf(-(t[4] + pat_b[0])));
    float l0 = t[1] + base_b[0], l1 = t[2] + base_b[1], l2 = t[3] + base_b[2];
    float m = fmaxf(l0, fmaxf(l1, l2));
    float e0 = expf(l0 - m), e1 = expf(l1 - m), e2 = expf(l2 - m);
    float inv = 1.f / (e0 + e1 + e2);
    bool use_pat = (score > 0.f) && (p >= 0.5f);
    float o0, o1, o2;
    if (use_pat) { o0 = p; o1 = 0.5f * (1.f - p); o2 = o1; }
    else         { o0 = e0 * inv; o1 = e1 * inv; o2 = e2 * inv; }
    out[b * 3 + 0] = o0;
    out[b * 3 + 1] = o1;
    out[b * 3 + 2] = o2;
}

extern "C" void kernel_launch(void* const* d_in, const int* in_sizes, int n_in,
                              void* d_out, int out_size, void* d_ws, size_t ws_size,
                              hipStream_t stream) {
    const float* in      = (const float*)d_in[0];
    const float* conv_w  = (const float*)d_in[1];
    const float* conv_b  = (const float*)d_in[2];
    const float* match_w = (const float*)d_in[3];
    const float* match_b = (const float*)d_in[4];
    const float* pat_w   = (const float*)d_in[5];
    const float* pat_b   = (const float*)d_in[6];
    const float* base_w  = (const float*)d_in[7];
    const float* base_b  = (const float*)d_in[8];
    const int*   psi     = (const int*)d_in[9];
    float* out = (float*)d_out;

    float4* wq2  = (float4*)d_ws;                              // 2 MB
    float*  part = (float*)((char*)d_ws + (size_t)131072 * 16);  // 4*5*256 floats

    prep_weights<<<512, 256, 0, stream>>>(base_w, pat_w, psi, wq2);

    int B = in_sizes[0] / (64 * 64 * 3);   // 256
    pattern_branch_kernel<<<4 * B, TPB, 0, stream>>>(
        in, conv_w, conv_b, match_w, wq2, part);

    finalize_kernel<<<1, 256, 0, stream>>>(part, match_b, pat_b, base_b, out);
}